// Round 1
// baseline (200.415 us; speedup 1.0000x reference)
//
#include <hip/hip_runtime.h>

#define B_IMG 32
#define N_PIX (512 * 512)
#define NB 4096          // bins: err bits >> 19  (sign=0, 8 exp bits, 4 mantissa bits)
#define SHIFT 19
#define BPI 64           // blocks per image
#define CHUNK (N_PIX / BPI)   // 4096 elements per block

// ---------------- Pass 1: per-image histogram (count + sum) ----------------
__global__ __launch_bounds__(256) void hist_kernel(
    const float4* __restrict__ pred, const float4* __restrict__ targ,
    const int4* __restrict__ mask, unsigned* __restrict__ g_cnt,
    float* __restrict__ g_sum, unsigned* __restrict__ g_M) {
  __shared__ unsigned s_cnt[NB];
  __shared__ float s_sum[NB];
  const int tid = threadIdx.x;
  for (int i = tid; i < NB; i += 256) { s_cnt[i] = 0u; s_sum[i] = 0.f; }
  __syncthreads();

  const int img = blockIdx.x >> 6;        // / BPI
  const int blk = blockIdx.x & (BPI - 1);
  const int base4 = img * (N_PIX / 4) + blk * (CHUNK / 4);

  unsigned valid = 0;
#pragma unroll
  for (int j = 0; j < CHUNK / 4 / 256; ++j) {   // 4 iterations
    const int idx = base4 + j * 256 + tid;
    const float4 p = pred[idx];
    const float4 t = targ[idx];
    const int4 m = mask[idx];
    if (m.x > 0) { float e = fabsf(p.x - t.x); unsigned b = __float_as_uint(e) >> SHIFT; atomicAdd(&s_cnt[b], 1u); atomicAdd(&s_sum[b], e); ++valid; }
    if (m.y > 0) { float e = fabsf(p.y - t.y); unsigned b = __float_as_uint(e) >> SHIFT; atomicAdd(&s_cnt[b], 1u); atomicAdd(&s_sum[b], e); ++valid; }
    if (m.z > 0) { float e = fabsf(p.z - t.z); unsigned b = __float_as_uint(e) >> SHIFT; atomicAdd(&s_cnt[b], 1u); atomicAdd(&s_sum[b], e); ++valid; }
    if (m.w > 0) { float e = fabsf(p.w - t.w); unsigned b = __float_as_uint(e) >> SHIFT; atomicAdd(&s_cnt[b], 1u); atomicAdd(&s_sum[b], e); ++valid; }
  }
  __syncthreads();

  // flush nonzero bins to per-image global histogram
  for (int i = tid; i < NB; i += 256) {
    const unsigned c = s_cnt[i];
    if (c) {
      atomicAdd(&g_cnt[img * NB + i], c);
      atomicAdd(&g_sum[img * NB + i], s_sum[i]);
    }
  }
  // reduce valid count within wave, one atomic per wave
  for (int off = 32; off > 0; off >>= 1) valid += __shfl_down(valid, off);
  if ((tid & 63) == 0) atomicAdd(&g_M[img], valid);
}

// ---------------- Pass 2: per-image selection + trimmed sum ----------------
__global__ __launch_bounds__(256) void finalize_kernel(
    const unsigned* __restrict__ g_cnt, const float* __restrict__ g_sum,
    const unsigned* __restrict__ g_M, double* __restrict__ accs) {
  const int b = blockIdx.x;
  const int tid = threadIdx.x;   // 256 threads, 16 bins each
  const unsigned* cnt = g_cnt + b * NB;
  const float* sm = g_sum + b * NB;

  __shared__ unsigned s_part[256];
  __shared__ unsigned s_pref[256];
  __shared__ int s_bin;
  __shared__ unsigned s_cbelow;
  __shared__ double s_red[256];

  unsigned c[16];
  unsigned local = 0;
#pragma unroll
  for (int i = 0; i < 16; ++i) { c[i] = cnt[tid * 16 + i]; local += c[i]; }
  s_part[tid] = local;
  if (tid == 0) { s_bin = 0; s_cbelow = 0; }
  __syncthreads();
  if (tid == 0) {
    unsigned run = 0;
    for (int i = 0; i < 256; ++i) { s_pref[i] = run; run += s_part[i]; }
  }
  __syncthreads();

  const unsigned M = g_M[b];
  const unsigned k = (unsigned)floorf(0.8f * (float)M);   // floor(M * (1-trim)) in f32, matches ref

  if (k > 0) {
    const unsigned e = s_pref[tid];
    if (e < k && k <= e + local) {   // boundary falls inside this thread's 16 bins
      unsigned run = e;
#pragma unroll
      for (int i = 0; i < 16; ++i) {
        if (run < k && k <= run + c[i]) { s_bin = tid * 16 + i; s_cbelow = run; break; }
        run += c[i];
      }
    }
  }
  __syncthreads();

  const int bstar = s_bin;
  // sum of all fully-kept bins (index < bstar)
  double acc = 0.0;
#pragma unroll
  for (int i = 0; i < 16; ++i) {
    const int bin = tid * 16 + i;
    if (bin < bstar) acc += (double)sm[bin];
  }
  // partial boundary bin (thread 0)
  if (tid == 0 && k > 0) {
    const unsigned cb = cnt[bstar];
    const float sb = sm[bstar];
    const unsigned r = k - s_cbelow;   // 1 <= r <= cb
    double part;
    if (r >= cb) {
      part = (double)sb;               // exact: whole bin kept
    } else {
      const float lo = __uint_as_float((unsigned)bstar << SHIFT);
      const double mean = (double)sb / (double)cb;
      double h = mean - (double)lo;
      if (h < 0.0) h = 0.0;
      part = (double)r * (double)lo + ((double)r * (double)r / (double)cb) * h;
      if (part > (double)sb) part = (double)sb;
    }
    acc += part;
  }

  // block reduce doubles
  s_red[tid] = acc;
  __syncthreads();
  for (int s = 128; s > 0; s >>= 1) {
    if (tid < s) s_red[tid] += s_red[tid + s];
    __syncthreads();
  }
  if (tid == 0) {
    atomicAdd(&accs[0], s_red[0]);                         // numerator
    atomicAdd(&accs[1], (double)(0.8f * (float)M));        // divisor term, f32 like ref
  }
}

// ---------------- Pass 3: final divide ----------------
__global__ void final_kernel(const double* __restrict__ accs, float* __restrict__ out) {
  const double num = accs[0];
  const double den = accs[1];
  const double r = (den == 0.0) ? 0.0 : num / fmax(den, 1e-30);
  out[0] = (float)r;
}

extern "C" void kernel_launch(void* const* d_in, const int* in_sizes, int n_in,
                              void* d_out, int out_size, void* d_ws, size_t ws_size,
                              hipStream_t stream) {
  const float4* pred = (const float4*)d_in[0];
  const float4* targ = (const float4*)d_in[1];
  const int4* mask = (const int4*)d_in[2];
  float* out = (float*)d_out;

  char* ws = (char*)d_ws;
  unsigned* g_cnt = (unsigned*)ws;                                   // B*NB*4 = 512 KB
  float* g_sum = (float*)(ws + (size_t)B_IMG * NB * 4);              // 512 KB
  double* accs = (double*)(ws + (size_t)2 * B_IMG * NB * 4);         // 16 B
  unsigned* g_M = (unsigned*)(ws + (size_t)2 * B_IMG * NB * 4 + 16); // 128 B

  const size_t zero_bytes = (size_t)2 * B_IMG * NB * 4 + 16 + B_IMG * 4;
  hipMemsetAsync(d_ws, 0, zero_bytes, stream);

  hist_kernel<<<B_IMG * BPI, 256, 0, stream>>>(pred, targ, mask, g_cnt, g_sum, g_M);
  finalize_kernel<<<B_IMG, 256, 0, stream>>>(g_cnt, g_sum, g_M, accs);
  final_kernel<<<1, 1, 0, stream>>>(accs, out);
}

// Round 2
// 175.288 us; speedup vs baseline: 1.1434x; 1.1434x over previous
//
#include <hip/hip_runtime.h>

#define B_IMG 32
#define N_PIX (512 * 512)
#define NB 256            // 16 octaves x 16 sub-bins (4 mantissa bits)
#define SHIFT 19
#define LO_IDX 1840       // (exp_biased=115) << 4  => clamp range 2^-12 .. 2^3
#define BPI 64            // blocks per image
#define CHUNK (N_PIX / BPI)   // 4096 elements per block

// ---------------- Pass 1: per-image histogram (count + sum) ----------------
__global__ __launch_bounds__(256) void hist_kernel(
    const float4* __restrict__ pred, const float4* __restrict__ targ,
    const int4* __restrict__ mask, unsigned* __restrict__ g_cnt,
    float* __restrict__ g_sum, unsigned* __restrict__ g_M) {
  __shared__ unsigned s_cnt[NB];
  __shared__ float s_sum[NB];
  const int tid = threadIdx.x;
  if (tid < NB) { s_cnt[tid] = 0u; s_sum[tid] = 0.f; }
  __syncthreads();

  const int img = blockIdx.x >> 6;        // / BPI
  const int blk = blockIdx.x & (BPI - 1);
  const int base4 = img * (N_PIX / 4) + blk * (CHUNK / 4);

  // Batch ALL loads up-front: 12 independent 16B loads in flight per lane.
  float4 p[4], t[4];
  int4 m[4];
#pragma unroll
  for (int j = 0; j < 4; ++j) p[j] = pred[base4 + j * 256 + tid];
#pragma unroll
  for (int j = 0; j < 4; ++j) t[j] = targ[base4 + j * 256 + tid];
#pragma unroll
  for (int j = 0; j < 4; ++j) m[j] = mask[base4 + j * 256 + tid];

  unsigned valid = 0;
#pragma unroll
  for (int j = 0; j < 4; ++j) {
    const float pe[4] = {p[j].x, p[j].y, p[j].z, p[j].w};
    const float te[4] = {t[j].x, t[j].y, t[j].z, t[j].w};
    const int me[4] = {m[j].x, m[j].y, m[j].z, m[j].w};
#pragma unroll
    for (int q = 0; q < 4; ++q) {
      if (me[q] > 0) {
        const float e = fabsf(pe[q] - te[q]);
        int b = (int)(__float_as_uint(e) >> SHIFT) - LO_IDX;
        b = b < 0 ? 0 : (b > NB - 1 ? NB - 1 : b);
        atomicAdd(&s_cnt[b], 1u);
        atomicAdd(&s_sum[b], e);
        ++valid;
      }
    }
  }
  __syncthreads();

  // flush to per-image global histogram (1 bin per thread)
  if (tid < NB) {
    const unsigned c = s_cnt[tid];
    if (c) {
      atomicAdd(&g_cnt[img * NB + tid], c);
      atomicAdd(&g_sum[img * NB + tid], s_sum[tid]);
    }
  }
  // reduce valid count within wave, one atomic per wave
  for (int off = 32; off > 0; off >>= 1) valid += __shfl_down(valid, off);
  if ((tid & 63) == 0) atomicAdd(&g_M[img], valid);
}

// ---------------- Pass 2: per-image selection + trimmed sum ----------------
__global__ __launch_bounds__(256) void finalize_kernel(
    const unsigned* __restrict__ g_cnt, const float* __restrict__ g_sum,
    const unsigned* __restrict__ g_M, double* __restrict__ accs) {
  const int b = blockIdx.x;
  const int tid = threadIdx.x;   // 256 threads, one bin each

  const unsigned c = g_cnt[b * NB + tid];
  const float s = g_sum[b * NB + tid];

  // Hillis-Steele inclusive scan of counts over 256 threads
  __shared__ unsigned s_scan[NB];
  __shared__ int s_bin;
  __shared__ unsigned s_cbelow;
  __shared__ double s_red[NB];

  s_scan[tid] = c;
  if (tid == 0) { s_bin = 0; s_cbelow = 0; }
  __syncthreads();
#pragma unroll
  for (int off = 1; off < NB; off <<= 1) {
    const unsigned add = (tid >= off) ? s_scan[tid - off] : 0u;
    __syncthreads();
    s_scan[tid] += add;
    __syncthreads();
  }
  const unsigned incl = s_scan[tid];
  const unsigned excl = incl - c;

  const unsigned M = g_M[b];
  const unsigned k = (unsigned)floorf(0.8f * (float)M);   // matches ref's floor(M*0.8) in f32

  if (k > 0 && excl < k && k <= incl) { s_bin = tid; s_cbelow = excl; }
  __syncthreads();

  const int bstar = s_bin;
  double acc = (tid < bstar) ? (double)s : 0.0;   // full bins below boundary: exact
  if (tid == bstar && k > 0) {
    const unsigned r = k - s_cbelow;   // 1 <= r <= c
    double part;
    if (r >= c) {
      part = (double)s;                // exact: whole bin kept
    } else {
      const float lo = __uint_as_float((unsigned)(bstar + LO_IDX) << SHIFT);
      const double mean = (double)s / (double)c;
      double h = mean - (double)lo;
      if (h < 0.0) h = 0.0;
      part = (double)r * (double)lo + ((double)r * (double)r / (double)c) * h;
      if (part > (double)s) part = (double)s;
    }
    acc += part;
  }

  // block reduce doubles
  s_red[tid] = acc;
  __syncthreads();
  for (int st = 128; st > 0; st >>= 1) {
    if (tid < st) s_red[tid] += s_red[tid + st];
    __syncthreads();
  }
  if (tid == 0) {
    atomicAdd(&accs[0], s_red[0]);                         // numerator
    atomicAdd(&accs[1], (double)(0.8f * (float)M));        // divisor term
  }
}

// ---------------- Pass 3: final divide ----------------
__global__ void final_kernel(const double* __restrict__ accs, float* __restrict__ out) {
  const double num = accs[0];
  const double den = accs[1];
  const double r = (den == 0.0) ? 0.0 : num / fmax(den, 1e-30);
  out[0] = (float)r;
}

extern "C" void kernel_launch(void* const* d_in, const int* in_sizes, int n_in,
                              void* d_out, int out_size, void* d_ws, size_t ws_size,
                              hipStream_t stream) {
  const float4* pred = (const float4*)d_in[0];
  const float4* targ = (const float4*)d_in[1];
  const int4* mask = (const int4*)d_in[2];
  float* out = (float*)d_out;

  char* ws = (char*)d_ws;
  unsigned* g_cnt = (unsigned*)ws;                                   // 32*256*4 = 32 KB
  float* g_sum = (float*)(ws + (size_t)B_IMG * NB * 4);              // 32 KB
  double* accs = (double*)(ws + (size_t)2 * B_IMG * NB * 4);         // 16 B
  unsigned* g_M = (unsigned*)(ws + (size_t)2 * B_IMG * NB * 4 + 16); // 128 B

  const size_t zero_bytes = (size_t)2 * B_IMG * NB * 4 + 16 + B_IMG * 4;
  hipMemsetAsync(d_ws, 0, zero_bytes, stream);

  hist_kernel<<<B_IMG * BPI, 256, 0, stream>>>(pred, targ, mask, g_cnt, g_sum, g_M);
  finalize_kernel<<<B_IMG, 256, 0, stream>>>(g_cnt, g_sum, g_M, accs);
  final_kernel<<<1, 1, 0, stream>>>(accs, out);
}

// Round 3
// 122.789 us; speedup vs baseline: 1.6322x; 1.4275x over previous
//
#include <hip/hip_runtime.h>

#define B_IMG 32
#define N_PIX (512 * 512)
#define NB 256            // 16 octaves x 16 sub-bins (4 mantissa bits)
#define SHIFT 19
#define LO_IDX 1840       // (exp_biased=115) << 4  => clamp range 2^-12 .. 2^3
#define BPI 64            // blocks per image
#define CHUNK (N_PIX / BPI)   // 4096 px per block
#define FIXSCALE 1048576.0f   // 2^20 fixed point for packed bin sums
#define MASK40 ((1ull << 40) - 1)

// ---------------- Pass 1: per-block partial histogram (packed u64) ----------------
// Packs per-bin {count, sum} into one u64: [63:40]=count, [39:0]=sum in 2^-20 fixed pt.
// Max per block: cnt<=4096 (24 bits ok), sum<=4096*16*2^20 < 2^37 (40 bits ok).
__global__ __launch_bounds__(256, 4) void hist_kernel(
    const float4* __restrict__ pred, const float4* __restrict__ targ,
    const int4* __restrict__ mask, unsigned long long* __restrict__ g_part,
    double* __restrict__ accs, unsigned* __restrict__ counter) {
  __shared__ unsigned long long s_hist[NB];
  const int tid = threadIdx.x;
  if (tid < NB) s_hist[tid] = 0ull;
  if (tid == 0) {  // zero the K2 accumulators; stream-ordered before K2 runs
    accs[0] = 0.0; accs[1] = 0.0; *counter = 0u;
  }
  __syncthreads();

  const int base4 = blockIdx.x * (CHUNK / 4);

#define BIN1(pp, tt, mm)                                                     \
  if ((mm) > 0) {                                                            \
    const float e = fabsf((pp) - (tt));                                      \
    int bb = (int)(__float_as_uint(e) >> SHIFT) - LO_IDX;                    \
    bb = bb < 0 ? 0 : (bb > NB - 1 ? NB - 1 : bb);                           \
    const unsigned long long pkt =                                           \
        (1ull << 40) | (unsigned long long)__float2uint_rn(e * FIXSCALE);    \
    atomicAdd(&s_hist[bb], pkt);                                             \
  }

  // double-buffered prefetch: batch j+1 loads in flight while binning batch j
  float4 p0 = pred[base4 + tid];
  float4 t0 = targ[base4 + tid];
  int4 m0 = mask[base4 + tid];
#pragma unroll
  for (int j = 0; j < 4; ++j) {
    float4 p1, t1;
    int4 m1;
    if (j < 3) {
      const int idx = base4 + (j + 1) * 256 + tid;
      p1 = pred[idx]; t1 = targ[idx]; m1 = mask[idx];
    }
    BIN1(p0.x, t0.x, m0.x)
    BIN1(p0.y, t0.y, m0.y)
    BIN1(p0.z, t0.z, m0.z)
    BIN1(p0.w, t0.w, m0.w)
    p0 = p1; t0 = t1; m0 = m1;
  }
  __syncthreads();

  // flush partial histogram: plain coalesced store, no atomics, no pre-zero needed
  if (tid < NB) g_part[(size_t)blockIdx.x * NB + tid] = s_hist[tid];
}

// ---------------- Pass 2: per-image selection + trimmed sum + final divide ----------------
__global__ __launch_bounds__(256) void finalize_kernel(
    const unsigned long long* __restrict__ g_part, double* __restrict__ accs,
    unsigned* __restrict__ counter, float* __restrict__ out) {
  const int b = blockIdx.x;
  const int tid = threadIdx.x;   // 256 threads, one bin each
  const unsigned long long* base = g_part + (size_t)b * BPI * NB;

  // reduce 64 partials for this image's bin `tid`
  unsigned long long fix = 0ull;
  unsigned c = 0u;
#pragma unroll 8
  for (int p = 0; p < BPI; ++p) {
    const unsigned long long v = base[(size_t)p * NB + tid];
    c += (unsigned)(v >> 40);
    fix += (v & MASK40);
  }
  const double s = (double)fix * (1.0 / (double)FIXSCALE);

  __shared__ unsigned s_scan[NB];
  __shared__ int s_bin;
  __shared__ unsigned s_cbelow;
  __shared__ double s_red[NB];

  s_scan[tid] = c;
  if (tid == 0) { s_bin = 0; s_cbelow = 0; }
  __syncthreads();
  // Hillis-Steele inclusive scan of counts
#pragma unroll
  for (int off = 1; off < NB; off <<= 1) {
    const unsigned add = (tid >= off) ? s_scan[tid - off] : 0u;
    __syncthreads();
    s_scan[tid] += add;
    __syncthreads();
  }
  const unsigned incl = s_scan[tid];
  const unsigned excl = incl - c;
  const unsigned M = s_scan[NB - 1];                      // all valid px land in a bin
  const unsigned k = (unsigned)floorf(0.8f * (float)M);   // matches ref's f32 floor

  if (k > 0 && excl < k && k <= incl) { s_bin = tid; s_cbelow = excl; }
  __syncthreads();

  const int bstar = s_bin;
  double acc = (tid < bstar) ? s : 0.0;   // full bins below boundary: exact sums
  if (tid == bstar && k > 0) {
    const unsigned r = k - s_cbelow;      // 1 <= r <= c
    double part;
    if (r >= c) {
      part = s;                           // exact: whole bin kept
    } else {
      const float lo = __uint_as_float((unsigned)(bstar + LO_IDX) << SHIFT);
      const double mean = s / (double)c;
      double h = mean - (double)lo;
      if (h < 0.0) h = 0.0;
      part = (double)r * (double)lo + ((double)r * (double)r / (double)c) * h;
      if (part > s) part = s;
    }
    acc += part;
  }

  // block reduce doubles
  s_red[tid] = acc;
  __syncthreads();
  for (int st = 128; st > 0; st >>= 1) {
    if (tid < st) s_red[tid] += s_red[tid + st];
    __syncthreads();
  }
  if (tid == 0) {
    atomicAdd(&accs[0], s_red[0]);                     // numerator
    atomicAdd(&accs[1], (double)(0.8f * (float)M));    // divisor term
    __threadfence();
    const unsigned old = atomicAdd(counter, 1u);
    if (old == (unsigned)(B_IMG - 1)) {                // last block finalizes
      __threadfence();
      const double num = atomicAdd(&accs[0], 0.0);
      const double den = atomicAdd(&accs[1], 0.0);
      const double r = (den == 0.0) ? 0.0 : num / fmax(den, 1e-30);
      out[0] = (float)r;
    }
  }
}

extern "C" void kernel_launch(void* const* d_in, const int* in_sizes, int n_in,
                              void* d_out, int out_size, void* d_ws, size_t ws_size,
                              hipStream_t stream) {
  const float4* pred = (const float4*)d_in[0];
  const float4* targ = (const float4*)d_in[1];
  const int4* mask = (const int4*)d_in[2];
  float* out = (float*)d_out;

  char* ws = (char*)d_ws;
  unsigned long long* g_part = (unsigned long long*)ws;            // 2048*256*8 = 4 MB
  double* accs = (double*)(ws + (size_t)B_IMG * BPI * NB * 8);     // 16 B
  unsigned* counter = (unsigned*)(ws + (size_t)B_IMG * BPI * NB * 8 + 16);

  hist_kernel<<<B_IMG * BPI, 256, 0, stream>>>(pred, targ, mask, g_part, accs, counter);
  finalize_kernel<<<B_IMG, 256, 0, stream>>>(g_part, accs, counter, out);
}